// Round 9
// baseline (251.337 us; speedup 1.0000x reference)
//
#include <hip/hip_runtime.h>
#include <hip/hip_bf16.h>

#define HDIM 2048
#define NHEADS 32
#define HEADD 64
#define NBATCH 2
#define SEQLEN 2048
#define MTOT (NBATCH * SEQLEN)
#define NQT64 32             // 32 q-tiles of 64 rows
#define LDQKV 6144           // fused QKV row stride

typedef __bf16 bf16;
typedef __bf16 bf16x8 __attribute__((ext_vector_type(8)));
typedef float f32x4 __attribute__((ext_vector_type(4)));
typedef float f32x8 __attribute__((ext_vector_type(8)));
typedef float f32x16 __attribute__((ext_vector_type(16)));

// global -> LDS async copy, 16B per lane; LDS dest is wave-uniform base + lane*16
__device__ __forceinline__ void gload_lds16(const bf16* g, bf16* l) {
  __builtin_amdgcn_global_load_lds(
      (const __attribute__((address_space(1))) void*)g,
      (__attribute__((address_space(3))) void*)l, 16, 0, 0);
}

__device__ __forceinline__ unsigned cvtpk_bf16(float lo, float hi) {
  unsigned r;
  asm("v_cvt_pk_bf16_f32 %0, %1, %2" : "=v"(r) : "v"(lo), "v"(hi));
  return r;
}

__device__ __forceinline__ float max3f(float a, float b, float c) {
  float r;
  asm("v_max3_f32 %0, %1, %2, %3" : "=v"(r) : "v"(a), "v"(b), "v"(c));
  return r;
}

__global__ void __launch_bounds__(256) cvt_f32_to_bf16(
    const float* __restrict__ src, bf16* __restrict__ dst, int n) {
  int i = (blockIdx.x * 256 + threadIdx.x) * 8;
  if (i >= n) return;
  f32x8 a = *(const f32x8*)(src + i);
  bf16x8 o;
#pragma unroll
  for (int j = 0; j < 8; ++j) o[j] = (bf16)a[j];
  *(bf16x8*)(dst + i) = o;
}

// 4 weight matrices in one dispatch (blockIdx.y selects)
__global__ void __launch_bounds__(256) cvt4_f32_to_bf16(
    const float* __restrict__ s0, const float* __restrict__ s1,
    const float* __restrict__ s2, const float* __restrict__ s3,
    bf16* __restrict__ d0, bf16* __restrict__ d1,
    bf16* __restrict__ d2, bf16* __restrict__ d3) {
  const float* src; bf16* dst;
  switch (blockIdx.y) {
    case 0: src = s0; dst = d0; break;
    case 1: src = s1; dst = d1; break;
    case 2: src = s2; dst = d2; break;
    default: src = s3; dst = d3; break;
  }
  int i = (blockIdx.x * 256 + threadIdx.x) * 8;
  f32x8 a = *(const f32x8*)(src + i);
  bf16x8 o;
#pragma unroll
  for (int j = 0; j < 8; ++j) o[j] = (bf16)a[j];
  *(bf16x8*)(dst + i) = o;
}

// pack bq|bk|bv -> biasqkv[6144]
__global__ void __launch_bounds__(256) pack_bias(
    const float* __restrict__ bq, const float* __restrict__ bk,
    const float* __restrict__ bv, float* __restrict__ out) {
  int i = blockIdx.x * 256 + threadIdx.x;
  if (i >= LDQKV) return;
  float v;
  if (i < HDIM) v = bq[i];
  else if (i < 2 * HDIM) v = bk[i - HDIM];
  else v = bv[i - 2 * HDIM];
  out[i] = v;
}

// ---------------------------------------------------------------------------
// QKV GEMM (R3 body, best measured: 107us / MfmaUtil 41%).
// 256x192 tile, 256 threads (4 waves, 2M x 2N), BK=32, grid 512 = 2/CU exact.
// LDS: A ring-2 + B ring-3 = 68 KB. 1 barrier/iter; vmcnt(3) counted (FIFO
// A(t+1) then B(t+2)). Hazard: stage at t overwrites regions last read t-1;
// vmcnt before barrier => WAR+RAW deterministic. Chunk swizzle c^=(row>>1)&3.
// ---------------------------------------------------------------------------
template <bool OUT_F32>
__global__ void __launch_bounds__(256, 2) gemmq(
    const bf16* __restrict__ A, const bf16* __restrict__ W,
    const float* __restrict__ bias, void* __restrict__ Cout,
    int Ndim, float scale) {
  constexpr int NT = 64;  // K-tiles (2048/32)
  __shared__ bf16 As[2][256 * 32];
  __shared__ bf16 Bs[3][192 * 32];

  const int tid = threadIdx.x;
  const int l = tid & 63;
  const int w = tid >> 6;   // 0..3
  const int wm = w >> 1;    // 0..1
  const int wn = w & 1;     // 0..1

  const int wid = blockIdx.x;
  const int j = wid >> 3;                       // 0..63
  const int m0 = ((wid & 7) * 2 + (j & 1)) * 256;
  const int n0 = (j >> 1) * 192;

  const int rowA = tid >> 2;                              // 0..63 (+ i*64)
  const int cg = (((tid & 3) ^ ((tid >> 3) & 3))) * 8;    // src col (bf16)

  auto stgA = [&](int s, int kt) {
    const bf16* g = A + (size_t)m0 * 2048 + kt * 32 + cg;
#pragma unroll
    for (int i = 0; i < 4; ++i)
      gload_lds16(g + (size_t)(i * 64 + rowA) * 2048,
                  &As[s][(i * 256 + w * 64) * 8]);
  };
  auto stgB = [&](int s, int kt) {
    const bf16* g = W + (size_t)n0 * 2048 + kt * 32 + cg;
#pragma unroll
    for (int i = 0; i < 3; ++i)
      gload_lds16(g + (size_t)(i * 64 + rowA) * 2048,
                  &Bs[s][(i * 256 + w * 64) * 8]);
  };

  f32x4 acc[8][6];
#pragma unroll
  for (int mf = 0; mf < 8; ++mf)
#pragma unroll
    for (int nf = 0; nf < 6; ++nf) acc[mf][nf] = {0.f, 0.f, 0.f, 0.f};

  const int fr = l & 15;
  const int fch = (((l >> 4) ^ ((fr >> 1) & 3))) * 8;  // bf16 offset in row
  const int abase = (wm * 128 + fr) * 32 + fch;
  const int bbase = (wn * 96 + fr) * 32 + fch;

  stgA(0, 0);
  stgB(0, 0);
  stgB(1, 1);
  asm volatile("s_waitcnt vmcnt(3)" ::: "memory");
  __builtin_amdgcn_s_barrier();

  int sb = 0;  // t % 3
  for (int t = 0; t < NT; ++t) {
    const int sa = t & 1;
    int sb2 = sb + 2; if (sb2 >= 3) sb2 -= 3;  // (t+2) % 3

    bf16x8 bf[6], af[4];
#pragma unroll
    for (int nf = 0; nf < 6; ++nf)
      bf[nf] = *(const bf16x8*)&Bs[sb][bbase + nf * 16 * 32];
#pragma unroll
    for (int f = 0; f < 4; ++f)
      af[f] = *(const bf16x8*)&As[sa][abase + f * 16 * 32];

    if (t + 1 < NT) stgA(sa ^ 1, t + 1);
    if (t + 2 < NT) stgB(sb2, t + 2);

    __builtin_amdgcn_s_setprio(1);
#pragma unroll
    for (int f = 0; f < 4; ++f)
#pragma unroll
      for (int nf = 0; nf < 6; ++nf)
        acc[f][nf] = __builtin_amdgcn_mfma_f32_16x16x32_bf16(
            af[f], bf[nf], acc[f][nf], 0, 0, 0);
    __builtin_amdgcn_s_setprio(0);

#pragma unroll
    for (int f = 0; f < 4; ++f)
      af[f] = *(const bf16x8*)&As[sa][abase + (4 + f) * 16 * 32];

    __builtin_amdgcn_s_setprio(1);
#pragma unroll
    for (int f = 0; f < 4; ++f)
#pragma unroll
      for (int nf = 0; nf < 6; ++nf)
        acc[4 + f][nf] = __builtin_amdgcn_mfma_f32_16x16x32_bf16(
            af[f], bf[nf], acc[4 + f][nf], 0, 0, 0);
    __builtin_amdgcn_s_setprio(0);

    if (t < NT - 2)
      asm volatile("s_waitcnt vmcnt(3)" ::: "memory");
    else
      asm volatile("s_waitcnt vmcnt(0)" ::: "memory");
    __builtin_amdgcn_s_barrier();

    sb = (sb == 2) ? 0 : sb + 1;
  }

  const int rj = (l >> 4) * 4;
#pragma unroll
  for (int mf = 0; mf < 8; ++mf)
#pragma unroll
    for (int nf = 0; nf < 6; ++nf) {
      const int col = n0 + wn * 96 + nf * 16 + fr;
      const float secsc = (col < 2048) ? scale : 1.0f;
      const float bvl = bias[col];
#pragma unroll
      for (int jj = 0; jj < 4; ++jj) {
        const int row = m0 + wm * 128 + mf * 16 + rj + jj;
        const float v = (acc[mf][nf][jj] + bvl) * secsc;
        if constexpr (OUT_F32)
          ((float*)Cout)[(size_t)row * Ndim + col] = v;
        else
          ((bf16*)Cout)[(size_t)row * Ndim + col] = (bf16)v;
      }
    }
}

// ---------------------------------------------------------------------------
// Output-projection GEMM: R3 structure, 128x128 tiles, 512 blocks = 2/CU.
// ---------------------------------------------------------------------------
__global__ void __launch_bounds__(256, 2) gemmp(
    const bf16* __restrict__ A, const bf16* __restrict__ W,
    const float* __restrict__ bias, float* __restrict__ Cout,
    int Ndim) {
  constexpr int NT = 64;  // K-tiles (2048/32)
  __shared__ bf16 As[2][128 * 32];
  __shared__ bf16 Bs[3][128 * 32];

  const int tid = threadIdx.x;
  const int l = tid & 63;
  const int w = tid >> 6;   // 0..3
  const int wm = w >> 1;    // 0..1
  const int wn = w & 1;     // 0..1

  const int wid = blockIdx.x;
  const int j = wid >> 3;                         // 0..63
  const int m0 = ((wid & 7) * 4 + (j & 3)) * 128;
  const int n0 = (j >> 2) * 128;

  const int rowA = tid >> 2;                              // 0..63 (+ i*64)
  const int cg = (((tid & 3) ^ ((tid >> 3) & 3))) * 8;    // src col (bf16)

  auto stgA = [&](int s, int kt) {
    const bf16* g = A + (size_t)m0 * 2048 + kt * 32 + cg;
#pragma unroll
    for (int i = 0; i < 2; ++i)
      gload_lds16(g + (size_t)(i * 64 + rowA) * 2048,
                  &As[s][(i * 256 + w * 64) * 8]);
  };
  auto stgB = [&](int s, int kt) {
    const bf16* g = W + (size_t)n0 * 2048 + kt * 32 + cg;
#pragma unroll
    for (int i = 0; i < 2; ++i)
      gload_lds16(g + (size_t)(i * 64 + rowA) * 2048,
                  &Bs[s][(i * 256 + w * 64) * 8]);
  };

  f32x4 acc[4][4];
#pragma unroll
  for (int mf = 0; mf < 4; ++mf)
#pragma unroll
    for (int nf = 0; nf < 4; ++nf) acc[mf][nf] = {0.f, 0.f, 0.f, 0.f};

  const int fr = l & 15;
  const int fch = (((l >> 4) ^ ((fr >> 1) & 3))) * 8;
  const int abase = (wm * 64 + fr) * 32 + fch;
  const int bbase = (wn * 64 + fr) * 32 + fch;

  stgA(0, 0);
  stgB(0, 0);
  stgB(1, 1);
  asm volatile("s_waitcnt vmcnt(2)" ::: "memory");
  __builtin_amdgcn_s_barrier();

  int sb = 0;  // t % 3
  for (int t = 0; t < NT; ++t) {
    const int sa = t & 1;
    int sb2 = sb + 2; if (sb2 >= 3) sb2 -= 3;  // (t+2) % 3

    bf16x8 bf[4], af[4];
#pragma unroll
    for (int nf = 0; nf < 4; ++nf)
      bf[nf] = *(const bf16x8*)&Bs[sb][bbase + nf * 16 * 32];
#pragma unroll
    for (int f = 0; f < 4; ++f)
      af[f] = *(const bf16x8*)&As[sa][abase + f * 16 * 32];

    if (t + 1 < NT) stgA(sa ^ 1, t + 1);
    if (t + 2 < NT) stgB(sb2, t + 2);

    __builtin_amdgcn_s_setprio(1);
#pragma unroll
    for (int f = 0; f < 4; ++f)
#pragma unroll
      for (int nf = 0; nf < 4; ++nf)
        acc[f][nf] = __builtin_amdgcn_mfma_f32_16x16x32_bf16(
            af[f], bf[nf], acc[f][nf], 0, 0, 0);
    __builtin_amdgcn_s_setprio(0);

    if (t < NT - 2)
      asm volatile("s_waitcnt vmcnt(2)" ::: "memory");
    else
      asm volatile("s_waitcnt vmcnt(0)" ::: "memory");
    __builtin_amdgcn_s_barrier();

    sb = (sb == 2) ? 0 : sb + 1;
  }

  const int rj = (l >> 4) * 4;
#pragma unroll
  for (int mf = 0; mf < 4; ++mf)
#pragma unroll
    for (int nf = 0; nf < 4; ++nf) {
      const int col = n0 + wn * 64 + nf * 16 + fr;
      const float bvl = bias[col];
#pragma unroll
      for (int jj = 0; jj < 4; ++jj) {
        const int row = m0 + wm * 64 + mf * 16 + rj + jj;
        Cout[(size_t)row * Ndim + col] = acc[mf][nf][jj] + bvl;
      }
    }
}

// One-shot V transpose: QKV [b][s][4096 + h*64+d] -> Vt [b][h][d][s]
__global__ void __launch_bounds__(256) transpose_v(
    const bf16* __restrict__ QKV, bf16* __restrict__ Vt) {
  __shared__ bf16 T[64][72];
  const int t = threadIdx.x;
  const int s0 = blockIdx.x * 64;
  const int h = blockIdx.y, b = blockIdx.z;
  const size_t inb = (size_t)b * SEQLEN * LDQKV + 2 * HDIM + (size_t)h * HEADD;
#pragma unroll
  for (int i = 0; i < 2; ++i) {
    const int idx = t + i * 256;
    const int r = idx >> 3, c = (idx & 7) * 8;
    *(bf16x8*)&T[r][c] = *(const bf16x8*)&QKV[inb + (size_t)(s0 + r) * LDQKV + c];
  }
  __syncthreads();
  const size_t outb = (size_t)(b * NHEADS + h) * HEADD * SEQLEN + s0;
#pragma unroll
  for (int i = 0; i < 2; ++i) {
    const int idx = t + i * 256;
    const int d = idx >> 3, cs = (idx & 7) * 8;
    bf16x8 o;
#pragma unroll
    for (int j = 0; j < 8; ++j) o[j] = T[cs + j][d];
    *(bf16x8*)&Vt[outb + (size_t)d * SEQLEN + cs] = o;
  }
}

// ---------------------------------------------------------------------------
// Flash attention, causal, swapped-QK 32x32 MFMA, in-register softmax (base-2).
// R9: per-wave compute body IDENTICAL to proven R5; geometry change only:
// 2-wave (128-thread) blocks on 64-row q-tiles, causally PAIRED.
// qt in 0..31, nkt = qt+1; block x handles seg0 qt=31-x, seg1 qt=x ->
// every block runs exactly 33 k-tile-steps (uniform). Grid = 16x32x2 = 1024
// blocks = 4/CU. The id-stride aliasing (ids k,k+256,k+512,k+768 share x)
// now gives each CU 4 blocks of IDENTICAL total work -- R7's +33% per-CU
// TLP throughput without its anti-balanced mapping. LDS ring-2 = 32KB/block
// -> 4 blocks = 128KB <= 160 (ring-2 requires the 2-barrier body: single
// barrier + ring-2 races under 1-iter wave skew). VGPR ~100 <= 128 (R6 rule).
// Staging (128 threads, 8 loads/stage): thread t, load i in 0..3 per array:
// chunk L = i*128+t -> row i*16+(t>>3), src col chunk (t&7)^((t>>3)&7)
// (i*16 = 0 mod 8 keeps swizzle alignment); LDS dest linear chunk L.
// vmcnt(8) at iter kt retires stage(kt) (8 loads in flight = stage(kt+1)).
// Q pre-scaled by 0.125*log2(e). Q,K in fused QKV; Vt [b][h][d][s].
// ---------------------------------------------------------------------------
__global__ void __launch_bounds__(128) attn4(
    const bf16* __restrict__ QKV, const bf16* __restrict__ Vt,
    bf16* __restrict__ O) {
  __shared__ bf16 Kl[2][64 * 64];  // [buf][kk][d], 16B-chunk XOR-swizzled
  __shared__ bf16 Vl[2][64 * 64];  // [buf][d][kk], 16B-chunk XOR-swizzled

  const int tid = threadIdx.x;
  const int l = tid & 63;
  const int w = tid >> 6;          // 0..1
  const int lq = l & 31;
  const int g = l >> 5;
  const int h = blockIdx.y, b = blockIdx.z;
  const size_t baseQ = (size_t)b * SEQLEN * LDQKV + (size_t)h * HEADD;
  const size_t baseK = baseQ + HDIM;
  const size_t baseV = (size_t)(b * NHEADS + h) * HEADD * SEQLEN;
  const size_t baseO = (size_t)b * SEQLEN * HDIM + (size_t)h * HEADD;

  // staging for 128 threads: 4 chunks per array per thread
  const int rs = tid >> 3;                            // 0..15 (+ i*16)
  const int gc = (((tid & 7) ^ ((tid >> 3) & 7))) * 8;  // src col (bf16)

  auto stage = [&](int bufi, int kt) {
    const int k0s = kt * 64;
#pragma unroll
    for (int i = 0; i < 4; ++i)
      gload_lds16(QKV + baseK + (size_t)(k0s + i * 16 + rs) * LDQKV + gc,
                  &Kl[bufi][(i * 128 + tid) * 8]);
#pragma unroll
    for (int i = 0; i < 4; ++i)
      gload_lds16(Vt + baseV + (size_t)(i * 16 + rs) * SEQLEN + k0s + gc,
                  &Vl[bufi][(i * 128 + tid) * 8]);
  };

#pragma unroll
  for (int seg = 0; seg < 2; ++seg) {
    const int qt = seg ? blockIdx.x : (NQT64 - 1 - blockIdx.x);  // heavy first
    const int q0 = qt * 64;
    const int qw = q0 + w * 32;
    const int qa = qw + lq;

    bf16x8 qf[4];
#pragma unroll
    for (int ks = 0; ks < 4; ++ks)
      qf[ks] = *(const bf16x8*)&QKV[baseQ + (size_t)qa * LDQKV + ks * 16 + g * 8];

    f32x16 oacc0, oacc1;
#pragma unroll
    for (int r = 0; r < 16; ++r) { oacc0[r] = 0.f; oacc1[r] = 0.f; }
    float mrun = -__builtin_inff(), lrun = 0.f;

    const int nkt = qt + 1;
    stage(0, 0);

    for (int kt = 0; kt < nkt; ++kt) {
      const int cur = kt & 1;
      const int k0 = kt * 64;
      if (kt + 1 < nkt) {
        stage(cur ^ 1, kt + 1);
        asm volatile("s_waitcnt vmcnt(8)" ::: "memory");
      } else {
        asm volatile("s_waitcnt vmcnt(0)" ::: "memory");
      }
      __builtin_amdgcn_s_barrier();

      if (k0 <= qw + 31) {
        f32x16 st0, st1;
#pragma unroll
        for (int r = 0; r < 16; ++r) { st0[r] = 0.f; st1[r] = 0.f; }
        __builtin_amdgcn_s_setprio(1);
#pragma unroll
        for (int ks = 0; ks < 4; ++ks) {
          const int cr = (((2 * ks + g) ^ (lq & 7))) * 8;
          bf16x8 kf0 = *(const bf16x8*)&Kl[cur][lq * 64 + cr];
          bf16x8 kf1 = *(const bf16x8*)&Kl[cur][(32 + lq) * 64 + cr];
          st0 = __builtin_amdgcn_mfma_f32_32x32x16_bf16(kf0, qf[ks], st0, 0, 0, 0);
          st1 = __builtin_amdgcn_mfma_f32_32x32x16_bf16(kf1, qf[ks], st1, 0, 0, 0);
        }
        __builtin_amdgcn_s_setprio(0);

        if (k0 + 63 > qw) {
#pragma unroll
          for (int r = 0; r < 16; ++r) {
            const int ro = (r & 3) + 8 * (r >> 2) + 4 * g;
            if (k0 + ro > qa) st0[r] = -__builtin_inff();
            if (k0 + 32 + ro > qa) st1[r] = -__builtin_inff();
          }
        }

        float mx[8];
#pragma unroll
        for (int r = 0; r < 8; ++r)
          mx[r] = fmaxf(max3f(st0[r], st0[r + 8], st1[r]), st1[r + 8]);
        const float ma = max3f(mx[0], mx[1], mx[2]);
        const float mb = max3f(mx[3], mx[4], mx[5]);
        const float mc = max3f(mx[6], mx[7], ma);
        const float mtree = fmaxf(mb, mc);
        const float pm = fmaxf(mtree, __shfl_xor(mtree, 32));

        const float mnew = fmaxf(mrun, pm);
        if (!__all(pm - mrun <= 11.0f)) {
          const float sc = __builtin_amdgcn_exp2f(mrun - mnew);
          lrun *= sc;
#pragma unroll
          for (int r = 0; r < 16; ++r) {
            const int ro = (r & 3) + 8 * (r >> 2) + 4 * g;
            const float scr = __shfl(sc, ro);
            oacc0[r] *= scr;
            oacc1[r] *= scr;
          }
          mrun = mnew;
        }

#pragma unroll
        for (int r = 0; r < 16; ++r) {
          st0[r] = __builtin_amdgcn_exp2f(st0[r] - mrun);
          st1[r] = __builtin_amdgcn_exp2f(st1[r] - mrun);
        }
        float sm[8];
#pragma unroll
        for (int r = 0; r < 8; ++r)
          sm[r] = (st0[r] + st0[r + 8]) + (st1[r] + st1[r + 8]);
#pragma unroll
        for (int s = 4; s > 0; s >>= 1)
#pragma unroll
          for (int r = 0; r < 4; ++r)
            if (r < s) sm[r] += sm[r + s];
        lrun += sm[0] + __shfl_xor(sm[0], 32);

        unsigned wd0[8], wd1[8];
#pragma unroll
        for (int i = 0; i < 8; ++i) {
          wd0[i] = cvtpk_bf16(st0[2 * i], st0[2 * i + 1]);
          wd1[i] = cvtpk_bf16(st1[2 * i], st1[2 * i + 1]);
        }
        bf16x8 paf[4];
#pragma unroll
        for (int kt2 = 0; kt2 < 2; ++kt2)
#pragma unroll
          for (int hf = 0; hf < 2; ++hf) {
            const unsigned* wsrc = kt2 ? wd1 : wd0;
            const unsigned a0 = wsrc[hf * 4 + 0], a1 = wsrc[hf * 4 + 1];
            const unsigned b0 = wsrc[hf * 4 + 2], b1 = wsrc[hf * 4 + 3];
            const unsigned sb0 = (unsigned)__shfl_xor((int)b0, 32);
            const unsigned sb1 = (unsigned)__shfl_xor((int)b1, 32);
            const unsigned sa0 = (unsigned)__shfl_xor((int)a0, 32);
            const unsigned sa1 = (unsigned)__shfl_xor((int)a1, 32);
            union { unsigned u[4]; bf16x8 v; } fu;
            fu.u[0] = g ? sb0 : a0;
            fu.u[1] = g ? sb1 : a1;
            fu.u[2] = g ? b0 : sa0;
            fu.u[3] = g ? b1 : sa1;
            paf[kt2 * 2 + hf] = fu.v;
          }

        __builtin_amdgcn_s_setprio(1);
#pragma unroll
        for (int s = 0; s < 4; ++s) {
          const int cr = (((2 * s + g) ^ (lq & 7))) * 8;
          bf16x8 vf0 = *(const bf16x8*)&Vl[cur][lq * 64 + cr];
          bf16x8 vf1 = *(const bf16x8*)&Vl[cur][(32 + lq) * 64 + cr];
          oacc0 = __builtin_amdgcn_mfma_f32_32x32x16_bf16(paf[s], vf0, oacc0, 0, 0, 0);
          oacc1 = __builtin_amdgcn_mfma_f32_32x32x16_bf16(paf[s], vf1, oacc1, 0, 0, 0);
        }
        __builtin_amdgcn_s_setprio(0);
      }
      __builtin_amdgcn_s_barrier();
    }

#pragma unroll
    for (int r = 0; r < 16; ++r) {
      const int ro = (r & 3) + 8 * (r >> 2) + 4 * g;
      const float lr = __shfl(lrun, ro);
      const float inv = 1.0f / lr;
      O[baseO + (size_t)(qw + ro) * HDIM + lq] = (bf16)(oacc0[r] * inv);
      O[baseO + (size_t)(qw + ro) * HDIM + 32 + lq] = (bf16)(oacc1[r] * inv);
    }
  }
}

extern "C" void kernel_launch(void* const* d_in, const int* in_sizes, int n_in,
                              void* d_out, int out_size, void* d_ws, size_t ws_size,
                              hipStream_t stream) {
  (void)in_sizes; (void)n_in; (void)out_size; (void)ws_size;
  const float* hs = (const float*)d_in[0];
  const float* wq = (const float*)d_in[1];
  const float* bq = (const float*)d_in[2];
  const float* wk = (const float*)d_in[3];
  const float* bk = (const float*)d_in[4];
  const float* wv = (const float*)d_in[5];
  const float* bv = (const float*)d_in[6];
  const float* wo = (const float*)d_in[7];
  const float* bo = (const float*)d_in[8];

  char* wsp = (char*)d_ws;
  bf16* hsb  = (bf16*)wsp; wsp += (size_t)MTOT * HDIM * sizeof(bf16);
  bf16* wqb  = (bf16*)wsp; wsp += (size_t)HDIM * HDIM * sizeof(bf16);
  bf16* wkb  = (bf16*)wsp; wsp += (size_t)HDIM * HDIM * sizeof(bf16);
  bf16* wvb  = (bf16*)wsp; wsp += (size_t)HDIM * HDIM * sizeof(bf16);
  bf16* wob  = (bf16*)wsp; wsp += (size_t)HDIM * HDIM * sizeof(bf16);
  bf16* QKVb = (bf16*)wsp; wsp += (size_t)MTOT * LDQKV * sizeof(bf16);
  float* biasqkv = (float*)wsp; wsp += (size_t)LDQKV * sizeof(float);
  bf16* aob = hsb;        // attn output aliases hsb (dead after QKV GEMM)
  bf16* Vtb = wqb;        // V^T aliases wqb+wkb (16MB, dead after QKV GEMM)

  const int nHS = MTOT * HDIM;
  const int nW = HDIM * HDIM;
  cvt_f32_to_bf16<<<nHS / 2048, 256, 0, stream>>>(hs, hsb, nHS);
  dim3 gc(nW / 2048, 4);
  cvt4_f32_to_bf16<<<gc, 256, 0, stream>>>(wq, wk, wv, wo, wqb, wkb, wvb, wob);
  pack_bias<<<LDQKV / 256, 256, 0, stream>>>(bq, bk, bv, biasqkv);

  // fused QKV GEMM: W = [wq|wk|wv], N=6144. 256x192 tiles -> 16*32 = 512
  // blocks = 2 blocks/CU x 256 CUs, exactly one round.
  // fold 1/sqrt(HD) * log2(e) into Q section for base-2 online softmax.
  gemmq<false><<<dim3(512), 256, 0, stream>>>(
      hsb, wqb, biasqkv, QKVb, LDQKV, 0.125f * 1.44269504f);

  dim3 gt(SEQLEN / 64, NHEADS, NBATCH);
  transpose_v<<<gt, 256, 0, stream>>>(QKVb, Vtb);

  // 2-wave blocks on paired 64-row q-tiles: 16x32x2 = 1024 blocks = 4/CU,
  // uniform 33 k-tile-steps per block.
  dim3 ga(NQT64 / 2, NHEADS, NBATCH);
  attn4<<<ga, 128, 0, stream>>>(QKVb, Vtb, aob);

  // output projection: 128x128 tiles -> 32*16 = 512 blocks = 2/CU, one round
  gemmp<<<dim3(512), 256, 0, stream>>>(aob, wob, bo, (float*)d_out, HDIM);
}

// Round 10
// 234.178 us; speedup vs baseline: 1.0733x; 1.0733x over previous
//
#include <hip/hip_runtime.h>
#include <hip/hip_bf16.h>

#define HDIM 2048
#define NHEADS 32
#define HEADD 64
#define NBATCH 2
#define SEQLEN 2048
#define MTOT (NBATCH * SEQLEN)
#define NQT (SEQLEN / 128)   // 16 q-tiles of 128 rows
#define LDQKV 6144           // fused QKV row stride

typedef __bf16 bf16;
typedef __bf16 bf16x8 __attribute__((ext_vector_type(8)));
typedef float f32x4 __attribute__((ext_vector_type(4)));
typedef float f32x8 __attribute__((ext_vector_type(8)));
typedef float f32x16 __attribute__((ext_vector_type(16)));

// global -> LDS async copy, 16B per lane; LDS dest is wave-uniform base + lane*16
__device__ __forceinline__ void gload_lds16(const bf16* g, bf16* l) {
  __builtin_amdgcn_global_load_lds(
      (const __attribute__((address_space(1))) void*)g,
      (__attribute__((address_space(3))) void*)l, 16, 0, 0);
}

__device__ __forceinline__ unsigned cvtpk_bf16(float lo, float hi) {
  unsigned r;
  asm("v_cvt_pk_bf16_f32 %0, %1, %2" : "=v"(r) : "v"(lo), "v"(hi));
  return r;
}

__device__ __forceinline__ float max3f(float a, float b, float c) {
  float r;
  asm("v_max3_f32 %0, %1, %2, %3" : "=v"(r) : "v"(a), "v"(b), "v"(c));
  return r;
}

// ---------------------------------------------------------------------------
// Fused prep: hs f32->bf16 (blocks 0..4095), 4 weight cvt (4096..12287),
// bias pack (12288..12311). One dispatch instead of three (saves launch gaps;
// all regions are independent elementwise).
// ---------------------------------------------------------------------------
__global__ void __launch_bounds__(256) prep_fused(
    const float* __restrict__ hs,
    const float* __restrict__ wq, const float* __restrict__ wk,
    const float* __restrict__ wv, const float* __restrict__ wo,
    const float* __restrict__ bq, const float* __restrict__ bk,
    const float* __restrict__ bv,
    bf16* __restrict__ hsb, bf16* __restrict__ wqb, bf16* __restrict__ wkb,
    bf16* __restrict__ wvb, bf16* __restrict__ wob,
    float* __restrict__ biasqkv) {
  const int bid = blockIdx.x;
  if (bid < 12288) {
    const float* src;
    bf16* dst;
    int blk;
    if (bid < 4096) {
      src = hs; dst = hsb; blk = bid;
    } else {
      const int r = bid - 4096;
      const int m = r >> 11;          // 0..3
      blk = r & 2047;
      switch (m) {
        case 0: src = wq; dst = wqb; break;
        case 1: src = wk; dst = wkb; break;
        case 2: src = wv; dst = wvb; break;
        default: src = wo; dst = wob; break;
      }
    }
    const int i = (blk * 256 + threadIdx.x) * 8;
    f32x8 a = *(const f32x8*)(src + i);
    bf16x8 o;
#pragma unroll
    for (int j = 0; j < 8; ++j) o[j] = (bf16)a[j];
    *(bf16x8*)(dst + i) = o;
  } else {
    const int i = (bid - 12288) * 256 + threadIdx.x;  // 0..6143
    float v;
    if (i < HDIM) v = bq[i];
    else if (i < 2 * HDIM) v = bk[i - HDIM];
    else v = bv[i - 2 * HDIM];
    biasqkv[i] = v;
  }
}

// ---------------------------------------------------------------------------
// QKV GEMM (R3 body, best measured: 107us / MfmaUtil 41%).
// 256x192 tile, 256 threads (4 waves, 2M x 2N), BK=32, grid 512 = 2/CU exact.
// LDS: A ring-2 + B ring-3 = 68 KB. 1 barrier/iter; vmcnt(3) counted (FIFO
// A(t+1) then B(t+2)). Hazard: stage at t overwrites regions last read t-1;
// vmcnt before barrier => WAR+RAW deterministic. Chunk swizzle c^=(row>>1)&3.
// ---------------------------------------------------------------------------
template <bool OUT_F32>
__global__ void __launch_bounds__(256, 2) gemmq(
    const bf16* __restrict__ A, const bf16* __restrict__ W,
    const float* __restrict__ bias, void* __restrict__ Cout,
    int Ndim, float scale) {
  constexpr int NT = 64;  // K-tiles (2048/32)
  __shared__ bf16 As[2][256 * 32];
  __shared__ bf16 Bs[3][192 * 32];

  const int tid = threadIdx.x;
  const int l = tid & 63;
  const int w = tid >> 6;   // 0..3
  const int wm = w >> 1;    // 0..1
  const int wn = w & 1;     // 0..1

  const int wid = blockIdx.x;
  const int j = wid >> 3;                       // 0..63
  const int m0 = ((wid & 7) * 2 + (j & 1)) * 256;
  const int n0 = (j >> 1) * 192;

  const int rowA = tid >> 2;                              // 0..63 (+ i*64)
  const int cg = (((tid & 3) ^ ((tid >> 3) & 3))) * 8;    // src col (bf16)

  auto stgA = [&](int s, int kt) {
    const bf16* g = A + (size_t)m0 * 2048 + kt * 32 + cg;
#pragma unroll
    for (int i = 0; i < 4; ++i)
      gload_lds16(g + (size_t)(i * 64 + rowA) * 2048,
                  &As[s][(i * 256 + w * 64) * 8]);
  };
  auto stgB = [&](int s, int kt) {
    const bf16* g = W + (size_t)n0 * 2048 + kt * 32 + cg;
#pragma unroll
    for (int i = 0; i < 3; ++i)
      gload_lds16(g + (size_t)(i * 64 + rowA) * 2048,
                  &Bs[s][(i * 256 + w * 64) * 8]);
  };

  f32x4 acc[8][6];
#pragma unroll
  for (int mf = 0; mf < 8; ++mf)
#pragma unroll
    for (int nf = 0; nf < 6; ++nf) acc[mf][nf] = {0.f, 0.f, 0.f, 0.f};

  const int fr = l & 15;
  const int fch = (((l >> 4) ^ ((fr >> 1) & 3))) * 8;  // bf16 offset in row
  const int abase = (wm * 128 + fr) * 32 + fch;
  const int bbase = (wn * 96 + fr) * 32 + fch;

  stgA(0, 0);
  stgB(0, 0);
  stgB(1, 1);
  asm volatile("s_waitcnt vmcnt(3)" ::: "memory");
  __builtin_amdgcn_s_barrier();

  int sb = 0;  // t % 3
  for (int t = 0; t < NT; ++t) {
    const int sa = t & 1;
    int sb2 = sb + 2; if (sb2 >= 3) sb2 -= 3;  // (t+2) % 3

    bf16x8 bf[6], af[4];
#pragma unroll
    for (int nf = 0; nf < 6; ++nf)
      bf[nf] = *(const bf16x8*)&Bs[sb][bbase + nf * 16 * 32];
#pragma unroll
    for (int f = 0; f < 4; ++f)
      af[f] = *(const bf16x8*)&As[sa][abase + f * 16 * 32];

    if (t + 1 < NT) stgA(sa ^ 1, t + 1);
    if (t + 2 < NT) stgB(sb2, t + 2);

    __builtin_amdgcn_s_setprio(1);
#pragma unroll
    for (int f = 0; f < 4; ++f)
#pragma unroll
      for (int nf = 0; nf < 6; ++nf)
        acc[f][nf] = __builtin_amdgcn_mfma_f32_16x16x32_bf16(
            af[f], bf[nf], acc[f][nf], 0, 0, 0);
    __builtin_amdgcn_s_setprio(0);

#pragma unroll
    for (int f = 0; f < 4; ++f)
      af[f] = *(const bf16x8*)&As[sa][abase + (4 + f) * 16 * 32];

    __builtin_amdgcn_s_setprio(1);
#pragma unroll
    for (int f = 0; f < 4; ++f)
#pragma unroll
      for (int nf = 0; nf < 6; ++nf)
        acc[4 + f][nf] = __builtin_amdgcn_mfma_f32_16x16x32_bf16(
            af[f], bf[nf], acc[4 + f][nf], 0, 0, 0);
    __builtin_amdgcn_s_setprio(0);

    if (t < NT - 2)
      asm volatile("s_waitcnt vmcnt(3)" ::: "memory");
    else
      asm volatile("s_waitcnt vmcnt(0)" ::: "memory");
    __builtin_amdgcn_s_barrier();

    sb = (sb == 2) ? 0 : sb + 1;
  }

  const int rj = (l >> 4) * 4;
#pragma unroll
  for (int mf = 0; mf < 8; ++mf)
#pragma unroll
    for (int nf = 0; nf < 6; ++nf) {
      const int col = n0 + wn * 96 + nf * 16 + fr;
      const float secsc = (col < 2048) ? scale : 1.0f;
      const float bvl = bias[col];
#pragma unroll
      for (int jj = 0; jj < 4; ++jj) {
        const int row = m0 + wm * 128 + mf * 16 + rj + jj;
        const float v = (acc[mf][nf][jj] + bvl) * secsc;
        if constexpr (OUT_F32)
          ((float*)Cout)[(size_t)row * Ndim + col] = v;
        else
          ((bf16*)Cout)[(size_t)row * Ndim + col] = (bf16)v;
      }
    }
}

// ---------------------------------------------------------------------------
// Output-projection GEMM: R3 structure, 128x128 tiles, 512 blocks = 2/CU.
// ---------------------------------------------------------------------------
__global__ void __launch_bounds__(256, 2) gemmp(
    const bf16* __restrict__ A, const bf16* __restrict__ W,
    const float* __restrict__ bias, float* __restrict__ Cout,
    int Ndim) {
  constexpr int NT = 64;  // K-tiles (2048/32)
  __shared__ bf16 As[2][128 * 32];
  __shared__ bf16 Bs[3][128 * 32];

  const int tid = threadIdx.x;
  const int l = tid & 63;
  const int w = tid >> 6;   // 0..3
  const int wm = w >> 1;    // 0..1
  const int wn = w & 1;     // 0..1

  const int wid = blockIdx.x;
  const int j = wid >> 3;                         // 0..63
  const int m0 = ((wid & 7) * 4 + (j & 3)) * 128;
  const int n0 = (j >> 2) * 128;

  const int rowA = tid >> 2;                              // 0..63 (+ i*64)
  const int cg = (((tid & 3) ^ ((tid >> 3) & 3))) * 8;    // src col (bf16)

  auto stgA = [&](int s, int kt) {
    const bf16* g = A + (size_t)m0 * 2048 + kt * 32 + cg;
#pragma unroll
    for (int i = 0; i < 2; ++i)
      gload_lds16(g + (size_t)(i * 64 + rowA) * 2048,
                  &As[s][(i * 256 + w * 64) * 8]);
  };
  auto stgB = [&](int s, int kt) {
    const bf16* g = W + (size_t)n0 * 2048 + kt * 32 + cg;
#pragma unroll
    for (int i = 0; i < 2; ++i)
      gload_lds16(g + (size_t)(i * 64 + rowA) * 2048,
                  &Bs[s][(i * 256 + w * 64) * 8]);
  };

  f32x4 acc[4][4];
#pragma unroll
  for (int mf = 0; mf < 4; ++mf)
#pragma unroll
    for (int nf = 0; nf < 4; ++nf) acc[mf][nf] = {0.f, 0.f, 0.f, 0.f};

  const int fr = l & 15;
  const int fch = (((l >> 4) ^ ((fr >> 1) & 3))) * 8;
  const int abase = (wm * 64 + fr) * 32 + fch;
  const int bbase = (wn * 64 + fr) * 32 + fch;

  stgA(0, 0);
  stgB(0, 0);
  stgB(1, 1);
  asm volatile("s_waitcnt vmcnt(2)" ::: "memory");
  __builtin_amdgcn_s_barrier();

  int sb = 0;  // t % 3
  for (int t = 0; t < NT; ++t) {
    const int sa = t & 1;
    int sb2 = sb + 2; if (sb2 >= 3) sb2 -= 3;  // (t+2) % 3

    bf16x8 bf[4], af[4];
#pragma unroll
    for (int nf = 0; nf < 4; ++nf)
      bf[nf] = *(const bf16x8*)&Bs[sb][bbase + nf * 16 * 32];
#pragma unroll
    for (int f = 0; f < 4; ++f)
      af[f] = *(const bf16x8*)&As[sa][abase + f * 16 * 32];

    if (t + 1 < NT) stgA(sa ^ 1, t + 1);
    if (t + 2 < NT) stgB(sb2, t + 2);

    __builtin_amdgcn_s_setprio(1);
#pragma unroll
    for (int f = 0; f < 4; ++f)
#pragma unroll
      for (int nf = 0; nf < 4; ++nf)
        acc[f][nf] = __builtin_amdgcn_mfma_f32_16x16x32_bf16(
            af[f], bf[nf], acc[f][nf], 0, 0, 0);
    __builtin_amdgcn_s_setprio(0);

    if (t < NT - 2)
      asm volatile("s_waitcnt vmcnt(2)" ::: "memory");
    else
      asm volatile("s_waitcnt vmcnt(0)" ::: "memory");
    __builtin_amdgcn_s_barrier();

    sb = (sb == 2) ? 0 : sb + 1;
  }

  const int rj = (l >> 4) * 4;
#pragma unroll
  for (int mf = 0; mf < 4; ++mf)
#pragma unroll
    for (int nf = 0; nf < 4; ++nf) {
      const int col = n0 + wn * 64 + nf * 16 + fr;
      const float bvl = bias[col];
#pragma unroll
      for (int jj = 0; jj < 4; ++jj) {
        const int row = m0 + wm * 64 + mf * 16 + rj + jj;
        Cout[(size_t)row * Ndim + col] = acc[mf][nf][jj] + bvl;
      }
    }
}

// One-shot V transpose: QKV [b][s][4096 + h*64+d] -> Vt [b][h][d][s]
__global__ void __launch_bounds__(256) transpose_v(
    const bf16* __restrict__ QKV, bf16* __restrict__ Vt) {
  __shared__ bf16 T[64][72];
  const int t = threadIdx.x;
  const int s0 = blockIdx.x * 64;
  const int h = blockIdx.y, b = blockIdx.z;
  const size_t inb = (size_t)b * SEQLEN * LDQKV + 2 * HDIM + (size_t)h * HEADD;
#pragma unroll
  for (int i = 0; i < 2; ++i) {
    const int idx = t + i * 256;
    const int r = idx >> 3, c = (idx & 7) * 8;
    *(bf16x8*)&T[r][c] = *(const bf16x8*)&QKV[inb + (size_t)(s0 + r) * LDQKV + c];
  }
  __syncthreads();
  const size_t outb = (size_t)(b * NHEADS + h) * HEADD * SEQLEN + s0;
#pragma unroll
  for (int i = 0; i < 2; ++i) {
    const int idx = t + i * 256;
    const int d = idx >> 3, cs = (idx & 7) * 8;
    bf16x8 o;
#pragma unroll
    for (int j = 0; j < 8; ++j) o[j] = T[cs + j][d];
    *(bf16x8*)&Vt[outb + (size_t)d * SEQLEN + cs] = o;
  }
}

// ---------------------------------------------------------------------------
// Flash attention, causal, swapped-QK 32x32 MFMA, in-register softmax (base-2).
// R10: R8 geometry+schedule (best measured: paired 128-row q-tiles, 256 thr,
// ring-4 K/V, stage-2-ahead, ONE barrier/iter, counted vmcnt 8/4/0) with one
// change: P-fragment exchange via v_permlane32_swap_b32 (8 VALU ops) instead
// of 16 ds_bpermute + 16 cndmask. Mapping verified on HW in R6 (passed,
// identical absmax): swap(pa=a0, qb=b0) yields pa'={a0.lo|b0.lo},
// qb'={a0.hi|b0.hi} == the old {g? partner : own} word pattern. In-place,
// register-neutral (R6 rule: VGPR must stay <=128; R6's regression was the
// +32-VGPR ping-pong state, not permlane).
// Hazard ledger (ring-4, single barrier): skew bounded to 1 iter; stage(t+2)
// target last read at compute(t-2), issuing wave passed BAR(t-1) which
// required all waves done with compute(t-2) => WAR deterministic. RAW:
// vmcnt(8) retires s(t) exactly ({s(t),s(t+1),s(t+2)} = 12 outstanding).
// Tails vmcnt(4)/vmcnt(0). Inter-seg barrier before seg1's stage(0/1).
// Q pre-scaled by 0.125*log2(e). Paired q-tiles (uniform 34 k-tiles/block).
// ---------------------------------------------------------------------------
__global__ void __launch_bounds__(256) attn4(
    const bf16* __restrict__ QKV, const bf16* __restrict__ Vt,
    bf16* __restrict__ O) {
  __shared__ bf16 Kl[4][64 * 64];  // [buf][kk][d], 16B-chunk XOR-swizzled
  __shared__ bf16 Vl[4][64 * 64];  // [buf][d][kk], 16B-chunk XOR-swizzled

  const int tid = threadIdx.x;
  const int l = tid & 63;
  const int w = tid >> 6;
  const int lq = l & 31;
  const int g = l >> 5;
  const int h = blockIdx.y, b = blockIdx.z;
  const size_t baseQ = (size_t)b * SEQLEN * LDQKV + (size_t)h * HEADD;
  const size_t baseK = baseQ + HDIM;
  const size_t baseV = (size_t)(b * NHEADS + h) * HEADD * SEQLEN;
  const size_t baseO = (size_t)b * SEQLEN * HDIM + (size_t)h * HEADD;

  const int L0 = w * 128 + l;
  const int L1 = w * 128 + 64 + l;
  const int r0 = L0 >> 3, gc0 = ((L0 & 7) ^ (r0 & 7)) * 8;
  const int r1 = L1 >> 3, gc1 = ((L1 & 7) ^ (r1 & 7)) * 8;
  const int dst0 = (w * 128) * 8;
  const int dst1 = (w * 128 + 64) * 8;

  auto stage = [&](int bufi, int kt) {
    const int k0s = kt * 64;
    gload_lds16(QKV + baseK + (size_t)(k0s + r0) * LDQKV + gc0, &Kl[bufi][dst0]);
    gload_lds16(QKV + baseK + (size_t)(k0s + r1) * LDQKV + gc1, &Kl[bufi][dst1]);
    gload_lds16(Vt + baseV + (size_t)r0 * SEQLEN + k0s + gc0, &Vl[bufi][dst0]);
    gload_lds16(Vt + baseV + (size_t)r1 * SEQLEN + k0s + gc1, &Vl[bufi][dst1]);
  };

#pragma unroll
  for (int seg = 0; seg < 2; ++seg) {
    const int qt = seg ? blockIdx.x : (NQT - 1 - blockIdx.x);  // heavy first
    const int q0 = qt * 128;
    const int qw = q0 + w * 32;
    const int qa = qw + lq;

    bf16x8 qf[4];
#pragma unroll
    for (int ks = 0; ks < 4; ++ks)
      qf[ks] = *(const bf16x8*)&QKV[baseQ + (size_t)qa * LDQKV + ks * 16 + g * 8];

    f32x16 oacc0, oacc1;
#pragma unroll
    for (int r = 0; r < 16; ++r) { oacc0[r] = 0.f; oacc1[r] = 0.f; }
    float mrun = -__builtin_inff(), lrun = 0.f;

    const int nkt = q0 / 64 + 2;
    stage(0, 0);
    stage(1, 1);

    for (int kt = 0; kt < nkt; ++kt) {
      const int cur = kt & 3;
      const int k0 = kt * 64;
      if (kt + 2 < nkt) stage((kt + 2) & 3, kt + 2);
      if (kt < nkt - 2)
        asm volatile("s_waitcnt vmcnt(8)" ::: "memory");
      else if (kt == nkt - 2)
        asm volatile("s_waitcnt vmcnt(4)" ::: "memory");
      else
        asm volatile("s_waitcnt vmcnt(0)" ::: "memory");
      __builtin_amdgcn_s_barrier();

      if (k0 <= qw + 31) {
        f32x16 st0, st1;
#pragma unroll
        for (int r = 0; r < 16; ++r) { st0[r] = 0.f; st1[r] = 0.f; }
        __builtin_amdgcn_s_setprio(1);
#pragma unroll
        for (int ks = 0; ks < 4; ++ks) {
          const int cr = (((2 * ks + g) ^ (lq & 7))) * 8;
          bf16x8 kf0 = *(const bf16x8*)&Kl[cur][lq * 64 + cr];
          bf16x8 kf1 = *(const bf16x8*)&Kl[cur][(32 + lq) * 64 + cr];
          st0 = __builtin_amdgcn_mfma_f32_32x32x16_bf16(kf0, qf[ks], st0, 0, 0, 0);
          st1 = __builtin_amdgcn_mfma_f32_32x32x16_bf16(kf1, qf[ks], st1, 0, 0, 0);
        }
        __builtin_amdgcn_s_setprio(0);

        if (k0 + 63 > qw) {
#pragma unroll
          for (int r = 0; r < 16; ++r) {
            const int ro = (r & 3) + 8 * (r >> 2) + 4 * g;
            if (k0 + ro > qa) st0[r] = -__builtin_inff();
            if (k0 + 32 + ro > qa) st1[r] = -__builtin_inff();
          }
        }

        float mx[8];
#pragma unroll
        for (int r = 0; r < 8; ++r)
          mx[r] = fmaxf(max3f(st0[r], st0[r + 8], st1[r]), st1[r + 8]);
        const float ma = max3f(mx[0], mx[1], mx[2]);
        const float mb = max3f(mx[3], mx[4], mx[5]);
        const float mc = max3f(mx[6], mx[7], ma);
        const float mtree = fmaxf(mb, mc);
        const float pm = fmaxf(mtree, __shfl_xor(mtree, 32));

        const float mnew = fmaxf(mrun, pm);
        if (!__all(pm - mrun <= 11.0f)) {
          const float sc = __builtin_amdgcn_exp2f(mrun - mnew);
          lrun *= sc;
#pragma unroll
          for (int r = 0; r < 16; ++r) {
            const int ro = (r & 3) + 8 * (r >> 2) + 4 * g;
            const float scr = __shfl(sc, ro);
            oacc0[r] *= scr;
            oacc1[r] *= scr;
          }
          mrun = mnew;
        }

#pragma unroll
        for (int r = 0; r < 16; ++r) {
          st0[r] = __builtin_amdgcn_exp2f(st0[r] - mrun);
          st1[r] = __builtin_amdgcn_exp2f(st1[r] - mrun);
        }
        float sm[8];
#pragma unroll
        for (int r = 0; r < 8; ++r)
          sm[r] = (st0[r] + st0[r + 8]) + (st1[r] + st1[r + 8]);
#pragma unroll
        for (int s = 4; s > 0; s >>= 1)
#pragma unroll
          for (int r = 0; r < 4; ++r)
            if (r < s) sm[r] += sm[r + s];
        lrun += sm[0] + __shfl_xor(sm[0], 32);

        unsigned wd0[8], wd1[8];
#pragma unroll
        for (int i = 0; i < 8; ++i) {
          wd0[i] = cvtpk_bf16(st0[2 * i], st0[2 * i + 1]);
          wd1[i] = cvtpk_bf16(st1[2 * i], st1[2 * i + 1]);
        }
        bf16x8 paf[4];
#pragma unroll
        for (int kt2 = 0; kt2 < 2; ++kt2)
#pragma unroll
          for (int hf = 0; hf < 2; ++hf) {
            unsigned* wsrc = kt2 ? wd1 : wd0;
            unsigned pa = wsrc[hf * 4 + 0], pb = wsrc[hf * 4 + 1];
            unsigned qa2 = wsrc[hf * 4 + 2], qb2 = wsrc[hf * 4 + 3];
            // a' = {a.lo|b.lo}, b' = {a.hi|b.hi} -- both exchange words in
            // 2 VALU ops (verified vs shfl_xor version in R6: identical out)
            asm("v_permlane32_swap_b32 %0, %1" : "+v"(pa), "+v"(qa2));
            asm("v_permlane32_swap_b32 %0, %1" : "+v"(pb), "+v"(qb2));
            union { unsigned u[4]; bf16x8 v; } fu;
            fu.u[0] = pa; fu.u[1] = pb; fu.u[2] = qa2; fu.u[3] = qb2;
            paf[kt2 * 2 + hf] = fu.v;
          }

        __builtin_amdgcn_s_setprio(1);
#pragma unroll
        for (int s = 0; s < 4; ++s) {
          const int cr = (((2 * s + g) ^ (lq & 7))) * 8;
          bf16x8 vf0 = *(const bf16x8*)&Vl[cur][lq * 64 + cr];
          bf16x8 vf1 = *(const bf16x8*)&Vl[cur][(32 + lq) * 64 + cr];
          oacc0 = __builtin_amdgcn_mfma_f32_32x32x16_bf16(paf[s], vf0, oacc0, 0, 0, 0);
          oacc1 = __builtin_amdgcn_mfma_f32_32x32x16_bf16(paf[s], vf1, oacc1, 0, 0, 0);
        }
        __builtin_amdgcn_s_setprio(0);
      }
      // single barrier per iter (at loop head); no trailing barrier
    }

#pragma unroll
    for (int r = 0; r < 16; ++r) {
      const int ro = (r & 3) + 8 * (r >> 2) + 4 * g;
      const float lr = __shfl(lrun, ro);
      const float inv = 1.0f / lr;
      O[baseO + (size_t)(qw + ro) * HDIM + lq] = (bf16)(oacc0[r] * inv);
      O[baseO + (size_t)(qw + ro) * HDIM + 32 + lq] = (bf16)(oacc1[r] * inv);
    }

    // inter-seg fence: seg1's stage(0/1) must not overwrite buffers other
    // waves may still be reading in seg0's final compute.
    __builtin_amdgcn_s_barrier();
  }
}

extern "C" void kernel_launch(void* const* d_in, const int* in_sizes, int n_in,
                              void* d_out, int out_size, void* d_ws, size_t ws_size,
                              hipStream_t stream) {
  (void)in_sizes; (void)n_in; (void)out_size; (void)ws_size;
  const float* hs = (const float*)d_in[0];
  const float* wq = (const float*)d_in[1];
  const float* bq = (const float*)d_in[2];
  const float* wk = (const float*)d_in[3];
  const float* bk = (const float*)d_in[4];
  const float* wv = (const float*)d_in[5];
  const float* bv = (const float*)d_in[6];
  const float* wo = (const float*)d_in[7];
  const float* bo = (const float*)d_in[8];

  char* wsp = (char*)d_ws;
  bf16* hsb  = (bf16*)wsp; wsp += (size_t)MTOT * HDIM * sizeof(bf16);
  bf16* wqb  = (bf16*)wsp; wsp += (size_t)HDIM * HDIM * sizeof(bf16);
  bf16* wkb  = (bf16*)wsp; wsp += (size_t)HDIM * HDIM * sizeof(bf16);
  bf16* wvb  = (bf16*)wsp; wsp += (size_t)HDIM * HDIM * sizeof(bf16);
  bf16* wob  = (bf16*)wsp; wsp += (size_t)HDIM * HDIM * sizeof(bf16);
  bf16* QKVb = (bf16*)wsp; wsp += (size_t)MTOT * LDQKV * sizeof(bf16);
  float* biasqkv = (float*)wsp; wsp += (size_t)LDQKV * sizeof(float);
  bf16* aob = hsb;        // attn output aliases hsb (dead after QKV GEMM)
  bf16* Vtb = wqb;        // V^T aliases wqb+wkb (16MB, dead after QKV GEMM)

  // fused prep: hs cvt (4096 blocks) + 4 weight cvts (8192) + bias pack (24)
  prep_fused<<<dim3(12312), 256, 0, stream>>>(
      hs, wq, wk, wv, wo, bq, bk, bv, hsb, wqb, wkb, wvb, wob, biasqkv);

  // fused QKV GEMM: W = [wq|wk|wv], N=6144. 256x192 tiles -> 16*32 = 512
  // blocks = 2 blocks/CU x 256 CUs, exactly one round.
  // fold 1/sqrt(HD) * log2(e) into Q section for base-2 online softmax.
  gemmq<false><<<dim3(512), 256, 0, stream>>>(
      hsb, wqb, biasqkv, QKVb, LDQKV, 0.125f * 1.44269504f);

  dim3 gt(SEQLEN / 64, NHEADS, NBATCH);
  transpose_v<<<gt, 256, 0, stream>>>(QKVb, Vtb);

  // paired q-tiles (uniform 34 k-tiles/block): 512 blocks = 2/CU
  dim3 ga(NQT / 2, NHEADS, NBATCH);
  attn4<<<ga, 256, 0, stream>>>(QKVb, Vtb, aob);

  // output projection: 128x128 tiles -> 32*16 = 512 blocks = 2/CU, one round
  gemmp<<<dim3(512), 256, 0, stream>>>(aob, wob, bo, (float*)d_out, HDIM);
}